// Round 13
// baseline (192.261 us; speedup 1.0000x reference)
//
#include <hip/hip_runtime.h>
#include <stdint.h>
#include <string.h>

// Exact global median-of-|x| + masked copy, one full-data pass.
// thr replicates jnp fp32 semantics: thr = (t*0.1f)/0.1f (RN).
//
// Round-12 structure (proven, 183.2us); single change: PLAIN vector store in
// mega_k instead of nontemporal (nt bypasses L2 write aggregation; the
// L3-protection rationale died when the pre-read pass was removed in R9).
// Exactness unconditional: scan20 verifies all invariants and the gated
// repair chain recomputes from scratch on any miss.

struct Ctrl {
  unsigned prefix, rank;
  float    thr;
  unsigned ovf, below, blo, bhi, flag;
  unsigned klo, khi, kloA, khiA, s2, cblo, pad0, pad1;
};

typedef float fx4 __attribute__((ext_vector_type(4)));

#define SEGS   1024u
#define SEGCAP 2048u
#define OCAP   131072u
#define MB     1024u
#define MT     512u

// Arena word offsets:
#define W_SEGCNT 32u        // seg_cnt (1024)
#define W_CHUNK  1056u      // chunkSums (512)
#define W_H20    4096u      // ulp hist (2^19)      [zeroed by mega]
#define W_H13R   528384u    // repair 13-bit (8192) [zeroed by scan20 on flag]
#define W_H18R   536576u    // repair 18-bit (262144)[zeroed by scan20 on flag]
#define CAND_BYTE_OFF 4194304u

// ---------------- fast path ----------------

__global__ __launch_bounds__(64) void setup_k(unsigned* arena, unsigned k0,
                                              unsigned Klo, unsigned Khi) {
  if (threadIdx.x == 0 && blockIdx.x == 0) {
    Ctrl* c = (Ctrl*)arena;
    c->prefix = 0u; c->rank = k0; c->thr = 0.0f;
    c->ovf = 0u; c->below = 0u; c->blo = 0u; c->bhi = 0u; c->flag = 0u;
    c->klo = Klo; c->khi = Khi;
    c->kloA = 0u; c->khiA = 0u; c->s2 = 0u; c->cblo = 0u;
  }
}

// The single full pass: zero h20, classify, count below, compact candidates.
// Hot loop is load->classify->store; candidate insertion is ballot-gated.
__global__ __launch_bounds__(MT) void mega_k(
    const uint4* __restrict__ x4, float4* __restrict__ o4, long long n4,
    const unsigned* __restrict__ xs, float* __restrict__ os, long long n,
    unsigned* __restrict__ arena, uint2* __restrict__ cand)
{
  __shared__ unsigned lcnt;
  __shared__ unsigned wred[8];
  Ctrl* ctrl = (Ctrl*)arena;
  unsigned* seg_cnt = arena + W_SEGCNT;
  unsigned* h20 = arena + W_H20;
  // zero h20 (exactly 1 word per thread: MB*MT = 2^19)
  {
    unsigned i = blockIdx.x * MT + threadIdx.x;
    if (i < (1u << 19)) h20[i] = 0u;
  }
  if (threadIdx.x == 0) lcnt = 0u;
  __syncthreads();
  const unsigned Klo = ctrl->klo, Khi = ctrl->khi;
  const unsigned span = Khi - Klo;
  uint2* __restrict__ seg = cand + (size_t)blockIdx.x * SEGCAP;
  uint2* __restrict__ ovf = cand + (size_t)SEGS * SEGCAP;
  unsigned below = 0;
  const long long stride = (long long)gridDim.x * blockDim.x;
  for (long long i = (long long)blockIdx.x * blockDim.x + threadIdx.x; i < n4; i += stride) {
    uint4 v = x4[i];
    fx4 w;
    bool anyc = false;
    #pragma unroll
    for (int c = 0; c < 4; ++c) {
      unsigned raw = (&v.x)[c];
      unsigned key = raw & 0x7fffffffu;
      w[c] = (key >= Khi) ? __uint_as_float(raw) : 0.0f;
      below += (key < Klo) ? 1u : 0u;
      anyc |= (key - Klo) < span;      // key in [Klo,Khi), unsigned trick
    }
    *(fx4*)&o4[i] = w;                 // plain store (was nontemporal)
    if (__ballot(anyc)) {              // wave-uniform, almost always false
      unsigned bidx = (unsigned)(i * 4);
      #pragma unroll
      for (int c = 0; c < 4; ++c) {
        unsigned raw = (&v.x)[c];
        unsigned key = raw & 0x7fffffffu;
        if ((key - Klo) < span) {
          unsigned pos = atomicAdd(&lcnt, 1u);
          uint2 e; e.x = raw; e.y = bidx + (unsigned)c;
          if (pos < SEGCAP) seg[pos] = e;
          else { unsigned op = atomicAdd(&ctrl->ovf, 1u); if (op < OCAP) ovf[op] = e; }
        }
      }
    }
  }
  for (long long t = n4 * 4 + (long long)blockIdx.x * blockDim.x + threadIdx.x; t < n; t += stride) {
    unsigned raw = xs[t];
    unsigned key = raw & 0x7fffffffu;
    os[t] = (key >= Khi) ? __uint_as_float(raw) : 0.0f;
    if (key < Klo) below++;
    else if (key < Khi) {
      unsigned pos = atomicAdd(&lcnt, 1u);
      uint2 e; e.x = raw; e.y = (unsigned)t;
      if (pos < SEGCAP) seg[pos] = e;
      else { unsigned op = atomicAdd(&ctrl->ovf, 1u); if (op < OCAP) ovf[op] = e; }
    }
  }
  for (int o = 32; o > 0; o >>= 1) below += __shfl_down(below, o, 64);
  if ((threadIdx.x & 63u) == 0u) wred[threadIdx.x >> 6] = below;
  __syncthreads();
  if (threadIdx.x == 0) {
    unsigned s = 0;
    for (int i = 0; i < 8; ++i) s += wred[i];
    atomicAdd(&ctrl->below, s);
    seg_cnt[blockIdx.x] = (lcnt < SEGCAP) ? lcnt : SEGCAP;
  }
}

// Candidate ulp-hist: h20[key - klo] via global atomics (~sparse hits).
__global__ __launch_bounds__(256) void cand20_k(
    const uint2* __restrict__ cand, const unsigned* __restrict__ seg_cnt,
    const Ctrl* __restrict__ ctrl, unsigned* __restrict__ h20)
{
  const unsigned klo = ctrl->klo;
  const uint2* __restrict__ seg = cand + (size_t)blockIdx.x * SEGCAP;
  unsigned cnt = seg_cnt[blockIdx.x];
  for (unsigned t = threadIdx.x; t < cnt; t += 256u) {
    unsigned idx = (seg[t].x & 0x7fffffffu) - klo;
    if (idx < (1u << 19)) atomicAdd(&h20[idx], 1u);
  }
  if (blockIdx.x == 0) {
    unsigned oc = ctrl->ovf; if (oc > OCAP) oc = OCAP;
    const uint2* __restrict__ ovf = cand + (size_t)SEGS * SEGCAP;
    for (unsigned t = threadIdx.x; t < oc; t += 256u) {
      unsigned idx = (ovf[t].x & 0x7fffffffu) - klo;
      if (idx < (1u << 19)) atomicAdd(&h20[idx], 1u);
    }
  }
}

// chunk sums (grid = nbins/1024 blocks).
__global__ __launch_bounds__(256) void scan_big1_k(
    const unsigned* __restrict__ hist, unsigned* __restrict__ chunkSums)
{
  __shared__ unsigned red[256];
  const unsigned base = blockIdx.x * 1024u;
  unsigned s = 0;
  for (unsigned i = threadIdx.x; i < 1024u; i += 256u) s += hist[base + i];
  red[threadIdx.x] = s;
  __syncthreads();
  for (unsigned off = 128; off > 0; off >>= 1) {
    if (threadIdx.x < off) red[threadIdx.x] += red[threadIdx.x + off];
    __syncthreads();
  }
  if (threadIdx.x == 0) chunkSums[blockIdx.x] = red[0];
}

// ulp-exact select + thr + invariant verification (+ lazy repair-hist zero).
__global__ __launch_bounds__(1024) void scan20_k(
    const unsigned* __restrict__ h20, const unsigned* __restrict__ cs,
    Ctrl* __restrict__ ctrl, unsigned k0,
    unsigned* __restrict__ h13r, unsigned* __restrict__ h18r)
{
  __shared__ unsigned csh[512];
  __shared__ unsigned sc[1024];
  __shared__ unsigned sel[3];
  __shared__ unsigned sh_key, sh_found, sh_bad;
  const unsigned t = threadIdx.x;
  if (t == 0) { sh_found = 0u; sh_bad = 0u; }
  if (t < 512) csh[t] = cs[t];
  __syncthreads();
  const unsigned klo = ctrl->klo, khi = ctrl->khi;
  const unsigned below = ctrl->below, ovf = ctrl->ovf;
  const unsigned range = khi - klo;
  const unsigned rc = k0 - below;     // may wrap; verified below
  if (t == 0) {
    unsigned run = 0, ci = 0, cb = 0;
    for (int i = 0; i < 512; ++i) {
      unsigned cnt = csh[i];
      if (rc >= run && rc < run + cnt) { ci = (unsigned)i; cb = run; }
      run += cnt;
    }
    sel[0] = ci; sel[1] = cb; sel[2] = run;   // run = total
  }
  __syncthreads();
  const unsigned ci = sel[0], cb = sel[1], total = sel[2];
  unsigned val = h20[ci * 1024u + t];
  sc[t] = val;
  __syncthreads();
  for (unsigned off = 1; off < 1024; off <<= 1) {
    unsigned add = (t >= off) ? sc[t - off] : 0u;
    __syncthreads();
    sc[t] += add;
    __syncthreads();
  }
  const unsigned incl = sc[t], excl = incl - val;
  const unsigned rr = rc - cb;
  if (val > 0 && rc < total && rr >= excl && rr < incl) {
    unsigned key = klo + ci * 1024u + t;
    sh_key = key; sh_found = 1u;
    if (key < klo + 4u || key + 4u >= khi) sh_bad = 1u;
  }
  __syncthreads();
  if (t == 0) {
    bool bad = (k0 < below) || (rc >= total) || (ovf > OCAP) ||
               (range > (1u << 19)) || (sh_found == 0u) || (sh_bad != 0u);
    if (!bad) {
      unsigned key = sh_key;
      float v = __uint_as_float(key);
      ctrl->thr = __fdiv_rn(__fmul_rn(v, 0.1f), 0.1f);
      ctrl->prefix = key;
      sel[0] = 0u;
    } else sel[0] = 1u;
  }
  __syncthreads();
  if (sel[0]) {
    for (unsigned i = t; i < 8192u; i += 1024u) h13r[i] = 0u;
    for (unsigned i = t; i < 262144u; i += 1024u) h18r[i] = 0u;
    __syncthreads();
    if (t == 0) ctrl->flag = 1u;
  }
}

// Scatter-fix surviving candidates (skipped when repair flagged).
__global__ __launch_bounds__(256) void fixup_k(
    const uint2* __restrict__ cand, const unsigned* __restrict__ seg_cnt,
    const Ctrl* __restrict__ ctrl, float* __restrict__ out)
{
  if (*(volatile const unsigned*)&ctrl->flag != 0u) return;
  const float thr = ctrl->thr;
  const uint2* __restrict__ seg = cand + (size_t)blockIdx.x * SEGCAP;
  unsigned cnt = seg_cnt[blockIdx.x];
  for (unsigned t = threadIdx.x; t < cnt; t += 256u) {
    uint2 e = seg[t];
    float v = __uint_as_float(e.x);
    if (fabsf(v) > thr) out[e.y] = v;
  }
  if (blockIdx.x == 0) {
    unsigned oc = ctrl->ovf; if (oc > OCAP) oc = OCAP;
    const uint2* __restrict__ ovf = cand + (size_t)SEGS * SEGCAP;
    for (unsigned t = threadIdx.x; t < oc; t += 256u) {
      uint2 e = ovf[t];
      float v = __uint_as_float(e.x);
      if (fabsf(v) > thr) out[e.y] = v;
    }
  }
}

// ---------------- gated repair chain (exactness guarantee) ----------------

__global__ __launch_bounds__(256) void r13_k(
    const uint4* __restrict__ x4, long long n4,
    const unsigned* __restrict__ xs, long long n,
    unsigned* __restrict__ h13r, const Ctrl* __restrict__ ctrl)
{
  if (*(volatile const unsigned*)&ctrl->flag == 0u) return;
  __shared__ unsigned lh[8192];
  for (unsigned i = threadIdx.x; i < 8192u; i += 256u) lh[i] = 0u;
  __syncthreads();
  const long long stride = (long long)gridDim.x * blockDim.x;
  for (long long i = (long long)blockIdx.x * blockDim.x + threadIdx.x; i < n4; i += stride) {
    uint4 v = x4[i];
    atomicAdd(&lh[(v.x & 0x7fffffffu) >> 18], 1u);
    atomicAdd(&lh[(v.y & 0x7fffffffu) >> 18], 1u);
    atomicAdd(&lh[(v.z & 0x7fffffffu) >> 18], 1u);
    atomicAdd(&lh[(v.w & 0x7fffffffu) >> 18], 1u);
  }
  for (long long t = n4 * 4 + (long long)blockIdx.x * blockDim.x + threadIdx.x; t < n; t += stride)
    atomicAdd(&lh[(xs[t] & 0x7fffffffu) >> 18], 1u);
  __syncthreads();
  for (unsigned j = threadIdx.x; j < 8192u; j += 256u) {
    unsigned s = lh[j];
    if (s) atomicAdd(&h13r[j], s);
  }
}

__global__ __launch_bounds__(1024) void rscan13_k(
    const unsigned* __restrict__ h, Ctrl* __restrict__ ctrl, unsigned k0)
{
  if (*(volatile const unsigned*)&ctrl->flag == 0u) return;
  __shared__ unsigned wsum[16], wbase[16];
  const unsigned t = threadIdx.x, lane = t & 63u, wid = t >> 6;
  const unsigned lo = t * 8u, hi = lo + 8u;
  unsigned s = 0;
  for (unsigned j = lo; j < hi; ++j) s += h[j];
  unsigned run = s;
  for (unsigned o = 1; o < 64; o <<= 1) {
    unsigned v = __shfl_up(run, o, 64);
    if (lane >= o) run += v;
  }
  if (lane == 63u) wsum[wid] = run;
  __syncthreads();
  if (t == 0) { unsigned acc = 0; for (int i = 0; i < 16; ++i) { wbase[i] = acc; acc += wsum[i]; } }
  __syncthreads();
  const unsigned base = wbase[wid] + run - s;
  if (s > 0 && k0 >= base && k0 < base + s) {
    unsigned c = base;
    for (unsigned j = lo; j < hi; ++j) {
      unsigned cnt = h[j];
      if (k0 < c + cnt) { ctrl->prefix = j; ctrl->rank = k0 - c; break; }
      c += cnt;
    }
  }
}

__global__ __launch_bounds__(256) void rh18_k(
    const uint4* __restrict__ x4, long long n4,
    const unsigned* __restrict__ xs, long long n,
    unsigned* __restrict__ h18r, const Ctrl* __restrict__ ctrl)
{
  if (*(volatile const unsigned*)&ctrl->flag == 0u) return;
  const unsigned prefix = ctrl->prefix;
  const long long stride = (long long)gridDim.x * blockDim.x;
  for (long long i = (long long)blockIdx.x * blockDim.x + threadIdx.x; i < n4; i += stride) {
    uint4 v = x4[i];
    unsigned a = v.x & 0x7fffffffu, b = v.y & 0x7fffffffu;
    unsigned c = v.z & 0x7fffffffu, d = v.w & 0x7fffffffu;
    if ((a >> 18) == prefix) atomicAdd(&h18r[a & 0x3ffffu], 1u);
    if ((b >> 18) == prefix) atomicAdd(&h18r[b & 0x3ffffu], 1u);
    if ((c >> 18) == prefix) atomicAdd(&h18r[c & 0x3ffffu], 1u);
    if ((d >> 18) == prefix) atomicAdd(&h18r[d & 0x3ffffu], 1u);
  }
  for (long long t = n4 * 4 + (long long)blockIdx.x * blockDim.x + threadIdx.x; t < n; t += stride) {
    unsigned u = xs[t] & 0x7fffffffu;
    if ((u >> 18) == prefix) atomicAdd(&h18r[u & 0x3ffffu], 1u);
  }
}

__global__ __launch_bounds__(1024) void rs18_k(
    const unsigned* __restrict__ h, Ctrl* __restrict__ ctrl)
{
  if (*(volatile const unsigned*)&ctrl->flag == 0u) return;
  __shared__ unsigned wsum[16], wbase[16];
  const unsigned t = threadIdx.x, lane = t & 63u, wid = t >> 6;
  const unsigned lo = t * 256u, hi = lo + 256u;
  const unsigned oldP = ctrl->prefix;
  const unsigned r = ctrl->rank;
  unsigned s = 0;
  for (unsigned j = lo; j < hi; ++j) s += h[j];
  unsigned run = s;
  for (unsigned o = 1; o < 64; o <<= 1) {
    unsigned v = __shfl_up(run, o, 64);
    if (lane >= o) run += v;
  }
  if (lane == 63u) wsum[wid] = run;
  __syncthreads();
  if (t == 0) { unsigned acc = 0; for (int i = 0; i < 16; ++i) { wbase[i] = acc; acc += wsum[i]; } }
  __syncthreads();
  const unsigned base = wbase[wid] + run - s;
  if (s > 0 && r >= base && r < base + s) {
    unsigned c = base;
    for (unsigned j = lo; j < hi; ++j) {
      unsigned cnt = h[j];
      if (r < c + cnt) {
        unsigned key = (oldP << 18) | j;
        float v = __uint_as_float(key);
        ctrl->thr = __fdiv_rn(__fmul_rn(v, 0.1f), 0.1f);
        ctrl->prefix = key;
        break;
      }
      c += cnt;
    }
  }
}

__global__ __launch_bounds__(256) void rmask_k(
    const float4* __restrict__ x4, float4* __restrict__ o4, long long n4,
    const float* __restrict__ xs, float* __restrict__ os, long long n,
    const Ctrl* __restrict__ ctrl)
{
  if (*(volatile const unsigned*)&ctrl->flag == 0u) return;
  const float thr = ctrl->thr;
  const long long stride = (long long)gridDim.x * blockDim.x;
  for (long long i = (long long)blockIdx.x * blockDim.x + threadIdx.x; i < n4; i += stride) {
    float4 v = x4[i];
    fx4 w;
    w[0] = (fabsf(v.x) <= thr) ? 0.0f : v.x;
    w[1] = (fabsf(v.y) <= thr) ? 0.0f : v.y;
    w[2] = (fabsf(v.z) <= thr) ? 0.0f : v.z;
    w[3] = (fabsf(v.w) <= thr) ? 0.0f : v.w;
    *(fx4*)&o4[i] = w;
  }
  for (long long t = n4 * 4 + (long long)blockIdx.x * blockDim.x + threadIdx.x; t < n; t += stride) {
    float v = xs[t];
    os[t] = (fabsf(v) <= thr) ? 0.0f : v;
  }
}

// ---------------- fallback path ----------------

__global__ __launch_bounds__(256) void zero_words_k(unsigned* __restrict__ p, long long nwords) {
  long long i = (long long)blockIdx.x * blockDim.x + threadIdx.x;
  long long s = (long long)gridDim.x * blockDim.x;
  for (; i < nwords; i += s) p[i] = 0u;
}

__global__ __launch_bounds__(64) void init_ctrl_k(Ctrl* c0, unsigned k0,
                                                  Ctrl* c1, unsigned k1) {
  if (threadIdx.x == 0 && blockIdx.x == 0) {
    c0->prefix = 0u; c0->rank = k0; c0->thr = 0.0f; c0->ovf = 0u;
    c1->prefix = 0u; c1->rank = k1; c1->thr = 0.0f; c1->ovf = 0u;
  }
}

__global__ __launch_bounds__(64) void combine_thr_k(Ctrl* a, const Ctrl* b,
                                                    float lw, float hw) {
  if (threadIdx.x == 0 && blockIdx.x == 0) {
    float v0 = __uint_as_float(a->prefix);
    float v1 = __uint_as_float(b->prefix);
    float tq = __fadd_rn(__fmul_rn(v0, lw), __fmul_rn(v1, hw));
    a->thr = __fdiv_rn(__fmul_rn(tq, 0.1f), 0.1f);
  }
}

__global__ __launch_bounds__(1024) void scan_stage_k(
    const unsigned* __restrict__ hist, int bits, Ctrl* __restrict__ ctrl)
{
  __shared__ unsigned wsum[16], wbase[16];
  const unsigned nb = 1u << bits;
  const unsigned per = (nb + 1023u) >> 10;
  const unsigned t = threadIdx.x, lane = t & 63u, wid = t >> 6;
  const unsigned lo = t * per;
  const unsigned hi = (lo + per < nb) ? (lo + per) : nb;
  const unsigned oldPrefix = ctrl->prefix;
  const unsigned r = ctrl->rank;
  unsigned s = 0;
  for (unsigned j = lo; j < hi; ++j) s += hist[j];
  unsigned run = s;
  for (unsigned o = 1; o < 64; o <<= 1) {
    unsigned v = __shfl_up(run, o, 64);
    if (lane >= o) run += v;
  }
  if (lane == 63u) wsum[wid] = run;
  __syncthreads();
  if (t == 0) { unsigned acc = 0; for (int i = 0; i < 16; ++i) { wbase[i] = acc; acc += wsum[i]; } }
  __syncthreads();
  const unsigned base = wbase[wid] + run - s;
  if (s > 0 && r >= base && r < base + s) {
    unsigned c = base;
    for (unsigned j = lo; j < hi; ++j) {
      unsigned cnt = hist[j];
      if (r < c + cnt) {
        ctrl->prefix = (oldPrefix << bits) | j;
        ctrl->rank = r - c;
        break;
      }
      c += cnt;
    }
  }
}

__global__ __launch_bounds__(256) void hist_stage_k(
    const uint4* __restrict__ x4, long long n4,
    const unsigned* __restrict__ xs, long long n,
    unsigned* __restrict__ hist,
    const Ctrl* __restrict__ ctrl,
    int shift, int bits)
{
  __shared__ unsigned lh[4096];
  const unsigned nb = 1u << bits;
  const bool lds = (bits <= 12);
  if (lds) {
    for (unsigned i = threadIdx.x; i < nb; i += blockDim.x) lh[i] = 0u;
    __syncthreads();
  }
  const unsigned prefix = ctrl->prefix;
  const int top = shift + bits;
  const unsigned m = nb - 1u;
  const long long stride = (long long)gridDim.x * blockDim.x;
  long long i = (long long)blockIdx.x * blockDim.x + threadIdx.x;
  for (; i < n4; i += stride) {
    uint4 v = x4[i];
    unsigned a = v.x & 0x7fffffffu;
    unsigned b = v.y & 0x7fffffffu;
    unsigned c = v.z & 0x7fffffffu;
    unsigned d = v.w & 0x7fffffffu;
    if (lds) {
      if ((a >> top) == prefix) atomicAdd(&lh[(a >> shift) & m], 1u);
      if ((b >> top) == prefix) atomicAdd(&lh[(b >> shift) & m], 1u);
      if ((c >> top) == prefix) atomicAdd(&lh[(c >> shift) & m], 1u);
      if ((d >> top) == prefix) atomicAdd(&lh[(d >> shift) & m], 1u);
    } else {
      if ((a >> top) == prefix) atomicAdd(&hist[(a >> shift) & m], 1u);
      if ((b >> top) == prefix) atomicAdd(&hist[(b >> shift) & m], 1u);
      if ((c >> top) == prefix) atomicAdd(&hist[(c >> shift) & m], 1u);
      if ((d >> top) == prefix) atomicAdd(&hist[(d >> shift) & m], 1u);
    }
  }
  long long t = n4 * 4 + (long long)blockIdx.x * blockDim.x + threadIdx.x;
  for (; t < n; t += stride) {
    unsigned u = xs[t] & 0x7fffffffu;
    if ((u >> top) == prefix) {
      if (lds) atomicAdd(&lh[(u >> shift) & m], 1u);
      else     atomicAdd(&hist[(u >> shift) & m], 1u);
    }
  }
  if (lds) {
    __syncthreads();
    for (unsigned j = threadIdx.x; j < nb; j += blockDim.x) {
      unsigned cv = lh[j];
      if (cv) atomicAdd(&hist[j], cv);
    }
  }
}

__global__ __launch_bounds__(1024) void scan_big2_k(
    const unsigned* __restrict__ hist, const unsigned* __restrict__ chunkSums,
    Ctrl* __restrict__ ctrl)
{
  __shared__ unsigned cs[512];
  __shared__ unsigned sc[1024];
  __shared__ unsigned sel[2];
  const unsigned t = threadIdx.x;
  const unsigned oldPrefix = ctrl->prefix;
  const unsigned r = ctrl->rank;
  if (t < 512) cs[t] = chunkSums[t];
  __syncthreads();
  if (t == 0) {
    unsigned run = 0, ci = 0, cb = 0;
    for (int i = 0; i < 512; ++i) {
      unsigned cnt = cs[i];
      if (r >= run && r < run + cnt) { ci = (unsigned)i; cb = run; }
      run += cnt;
    }
    sel[0] = ci; sel[1] = cb;
  }
  __syncthreads();
  const unsigned ci = sel[0], cb = sel[1];
  const unsigned val = hist[ci * 1024u + t];
  sc[t] = val;
  __syncthreads();
  for (unsigned off = 1; off < 1024; off <<= 1) {
    unsigned add = (t >= off) ? sc[t - off] : 0u;
    __syncthreads();
    sc[t] += add;
    __syncthreads();
  }
  const unsigned incl = sc[t];
  const unsigned excl = incl - val;
  const unsigned rr = r - cb;
  if (val > 0 && rr >= excl && rr < incl) {
    ctrl->prefix = (oldPrefix << 19) | (ci * 1024u + t);
    ctrl->rank = rr - excl;
  }
}

__global__ __launch_bounds__(256) void mask_k(
    const float4* __restrict__ x4, float4* __restrict__ o4, long long n4,
    const float* __restrict__ xs, float* __restrict__ os, long long n,
    const Ctrl* __restrict__ ctrl)
{
  const float thr = ctrl->thr;
  const long long stride = (long long)gridDim.x * blockDim.x;
  long long i = (long long)blockIdx.x * blockDim.x + threadIdx.x;
  for (; i < n4; i += stride) {
    float4 v = x4[i];
    float4 w;
    w.x = (fabsf(v.x) <= thr) ? 0.0f : v.x;
    w.y = (fabsf(v.y) <= thr) ? 0.0f : v.y;
    w.z = (fabsf(v.z) <= thr) ? 0.0f : v.z;
    w.w = (fabsf(v.w) <= thr) ? 0.0f : v.w;
    o4[i] = w;
  }
  long long t = n4 * 4 + (long long)blockIdx.x * blockDim.x + threadIdx.x;
  for (; t < n; t += stride) {
    float v = xs[t];
    os[t] = (fabsf(v) <= thr) ? 0.0f : v;
  }
}

// ---------------- launch ----------------

extern "C" void kernel_launch(void* const* d_in, const int* in_sizes, int n_in,
                              void* d_out, int out_size, void* d_ws, size_t ws_size,
                              hipStream_t stream)
{
  const float* x = (const float*)d_in[0];
  const long long N = (long long)in_sizes[0];
  const long long n4 = N >> 2;
  const uint4* x4 = (const uint4*)x;
  const unsigned* xbits = (const unsigned*)x;

  // jnp.quantile fp32 index math: idx = 0.5f * f32(N-1).
  float idxf = 0.5f * (float)(N - 1);
  float lowf = floorf(idxf);
  float highf = ceilf(idxf);
  float hw = idxf - lowf;
  float lw = 1.0f - hw;
  unsigned k0 = (unsigned)lowf;
  unsigned k1 = (unsigned)highf;
  int dual = (hw != 0.0f);
  if (!dual) k1 = k0;

  const size_t needC = CAND_BYTE_OFF + ((size_t)SEGS * SEGCAP + OCAP) * 8;  // ~21 MB

  if (!dual && N < (1ll << 32) && n4 >= (1ll << 20) && ws_size >= needC) {
    unsigned* arena = (unsigned*)d_ws;
    Ctrl* c0 = (Ctrl*)arena;
    unsigned* seg_cnt   = arena + W_SEGCNT;
    unsigned* chunkSums = arena + W_CHUNK;
    unsigned* h20       = arena + W_H20;
    unsigned* h13r      = arena + W_H13R;
    unsigned* h18r      = arena + W_H18R;
    uint2* cand = (uint2*)((char*)d_ws + CAND_BYTE_OFF);

    // Guessed candidate interval around median(|N(0,1)|)=0.674490.
    // Empirical-median sigma at N=90M is ~8.3e-5, so [0.6740,0.6750) gives
    // >=6-sigma margins with only ~57K candidates. Pure performance hint:
    // scan20 verifies exact invariants; gated repair recomputes on any miss.
    float flo = 0.6740f, fhi = 0.6750f;
    unsigned Klo, Khi;
    memcpy(&Klo, &flo, 4);
    memcpy(&Khi, &fhi, 4);

    setup_k<<<1, 64, 0, stream>>>(arena, k0, Klo, Khi);
    mega_k<<<MB, MT, 0, stream>>>(x4, (float4*)d_out, n4, xbits, (float*)d_out, N,
                                  arena, cand);
    cand20_k<<<SEGS, 256, 0, stream>>>(cand, seg_cnt, c0, h20);
    scan_big1_k<<<512, 256, 0, stream>>>(h20, chunkSums);
    scan20_k<<<1, 1024, 0, stream>>>(h20, chunkSums, c0, k0, h13r, h18r);
    fixup_k<<<SEGS, 256, 0, stream>>>(cand, seg_cnt, c0, (float*)d_out);
    // gated repair chain (early-exit when flag==0)
    r13_k<<<1024, 256, 0, stream>>>(x4, n4, xbits, N, h13r, c0);
    rscan13_k<<<1, 1024, 0, stream>>>(h13r, c0, k0);
    rh18_k<<<1024, 256, 0, stream>>>(x4, n4, xbits, N, h18r, c0);
    rs18_k<<<1, 1024, 0, stream>>>(h18r, c0);
    rmask_k<<<1024, 256, 0, stream>>>((const float4*)x, (float4*)d_out, n4,
                                      x, (float*)d_out, N, c0);
    return;
  }

  // ---------- fallback: two-full-hist structure with kernel zeroing ----------
  const size_t needA = 65536 + (size_t)(1u << 19) * 4;  // 2,162,688
  char* wsb = (char*)d_ws;
  char* arena = (ws_size >= needA) ? wsb : (char*)d_out;  // d_out fully rewritten at end
  Ctrl* c0 = (ws_size >= 128) ? (Ctrl*)wsb : (Ctrl*)arena;
  Ctrl* c1 = c0 + 1;
  unsigned* chunkSums = (unsigned*)(arena + 128);
  unsigned* h1 = (unsigned*)(arena + 4096);
  unsigned* h2 = (unsigned*)(arena + 65536);
  const long long zwords = (long long)(needA - 4096) / 4;

  zero_words_k<<<512, 256, 0, stream>>>((unsigned*)(arena + 4096), zwords);
  init_ctrl_k<<<1, 64, 0, stream>>>(c0, k0, (dual ? c1 : c0), k1);

  const int nchain = dual ? 2 : 1;
  for (int chain = 0; chain < nchain; ++chain) {
    Ctrl* cc = chain ? c1 : c0;
    if (chain) zero_words_k<<<512, 256, 0, stream>>>((unsigned*)(arena + 4096), zwords);
    hist_stage_k<<<2048, 256, 0, stream>>>(x4, n4, xbits, N, h1, cc, 19, 12);
    scan_stage_k<<<1, 1024, 0, stream>>>(h1, 12, cc);
    hist_stage_k<<<2048, 256, 0, stream>>>(x4, n4, xbits, N, h2, cc, 0, 19);
    scan_big1_k<<<512, 256, 0, stream>>>(h2, chunkSums);
    scan_big2_k<<<1, 1024, 0, stream>>>(h2, chunkSums, cc);
  }
  combine_thr_k<<<1, 64, 0, stream>>>(c0, (dual ? c1 : c0), lw, hw);
  mask_k<<<2048, 256, 0, stream>>>((const float4*)x, (float4*)d_out, n4,
                                   x, (float*)d_out, N, c0);
}

// Round 14
// 185.941 us; speedup vs baseline: 1.0340x; 1.0340x over previous
//
#include <hip/hip_runtime.h>
#include <stdint.h>
#include <string.h>

// Exact global median-of-|x| + masked copy, one full-data pass.
// thr replicates jnp fp32 semantics: thr = (t*0.1f)/0.1f (RN).
//
// Round-12 structure (proven, 183.2us, nt stores); single change: 2-deep
// unrolled hot loop in mega_k (two independent loads in flight per thread).
// Exactness unconditional: scan20 verifies all invariants and the gated
// repair chain recomputes from scratch on any miss.

struct Ctrl {
  unsigned prefix, rank;
  float    thr;
  unsigned ovf, below, blo, bhi, flag;
  unsigned klo, khi, kloA, khiA, s2, cblo, pad0, pad1;
};

typedef float fx4 __attribute__((ext_vector_type(4)));

#define SEGS   1024u
#define SEGCAP 2048u
#define OCAP   131072u
#define MB     1024u
#define MT     512u

// Arena word offsets:
#define W_SEGCNT 32u        // seg_cnt (1024)
#define W_CHUNK  1056u      // chunkSums (512)
#define W_H20    4096u      // ulp hist (2^19)      [zeroed by mega]
#define W_H13R   528384u    // repair 13-bit (8192) [zeroed by scan20 on flag]
#define W_H18R   536576u    // repair 18-bit (262144)[zeroed by scan20 on flag]
#define CAND_BYTE_OFF 4194304u

// ---------------- fast path ----------------

__global__ __launch_bounds__(64) void setup_k(unsigned* arena, unsigned k0,
                                              unsigned Klo, unsigned Khi) {
  if (threadIdx.x == 0 && blockIdx.x == 0) {
    Ctrl* c = (Ctrl*)arena;
    c->prefix = 0u; c->rank = k0; c->thr = 0.0f;
    c->ovf = 0u; c->below = 0u; c->blo = 0u; c->bhi = 0u; c->flag = 0u;
    c->klo = Klo; c->khi = Khi;
    c->kloA = 0u; c->khiA = 0u; c->s2 = 0u; c->cblo = 0u;
  }
}

__device__ __forceinline__ void insert_cands(
    uint4 v, unsigned bidx, unsigned Klo, unsigned span,
    unsigned* lcnt, uint2* __restrict__ seg,
    uint2* __restrict__ ovf, unsigned* __restrict__ ovfctr)
{
  #pragma unroll
  for (int c = 0; c < 4; ++c) {
    unsigned raw = (&v.x)[c];
    unsigned key = raw & 0x7fffffffu;
    if ((key - Klo) < span) {
      unsigned pos = atomicAdd(lcnt, 1u);
      uint2 e; e.x = raw; e.y = bidx + (unsigned)c;
      if (pos < SEGCAP) seg[pos] = e;
      else { unsigned op = atomicAdd(ovfctr, 1u); if (op < OCAP) ovf[op] = e; }
    }
  }
}

// The single full pass: zero h20, classify, count below, compact candidates.
// 2-deep unroll: two independent loads issued per iteration; candidate
// insertion ballot-gated (wave-uniform, almost always false).
__global__ __launch_bounds__(MT) void mega_k(
    const uint4* __restrict__ x4, float4* __restrict__ o4, long long n4,
    const unsigned* __restrict__ xs, float* __restrict__ os, long long n,
    unsigned* __restrict__ arena, uint2* __restrict__ cand)
{
  __shared__ unsigned lcnt;
  __shared__ unsigned wred[8];
  Ctrl* ctrl = (Ctrl*)arena;
  unsigned* seg_cnt = arena + W_SEGCNT;
  unsigned* h20 = arena + W_H20;
  // zero h20 (exactly 1 word per thread: MB*MT = 2^19)
  {
    unsigned i = blockIdx.x * MT + threadIdx.x;
    if (i < (1u << 19)) h20[i] = 0u;
  }
  if (threadIdx.x == 0) lcnt = 0u;
  __syncthreads();
  const unsigned Klo = ctrl->klo, Khi = ctrl->khi;
  const unsigned span = Khi - Klo;
  uint2* __restrict__ seg = cand + (size_t)blockIdx.x * SEGCAP;
  uint2* __restrict__ ovf = cand + (size_t)SEGS * SEGCAP;
  unsigned below = 0;
  const long long stride = (long long)gridDim.x * blockDim.x;
  long long i = (long long)blockIdx.x * blockDim.x + threadIdx.x;
  for (; i + stride < n4; i += 2 * stride) {
    uint4 v0 = x4[i];
    uint4 v1 = x4[i + stride];
    fx4 w0, w1;
    bool any0 = false, any1 = false;
    #pragma unroll
    for (int c = 0; c < 4; ++c) {
      unsigned raw = (&v0.x)[c];
      unsigned key = raw & 0x7fffffffu;
      w0[c] = (key >= Khi) ? __uint_as_float(raw) : 0.0f;
      below += (key < Klo) ? 1u : 0u;
      any0 |= (key - Klo) < span;
    }
    #pragma unroll
    for (int c = 0; c < 4; ++c) {
      unsigned raw = (&v1.x)[c];
      unsigned key = raw & 0x7fffffffu;
      w1[c] = (key >= Khi) ? __uint_as_float(raw) : 0.0f;
      below += (key < Klo) ? 1u : 0u;
      any1 |= (key - Klo) < span;
    }
    __builtin_nontemporal_store(w0, (fx4*)&o4[i]);
    __builtin_nontemporal_store(w1, (fx4*)&o4[i + stride]);
    if (__ballot(any0 || any1)) {
      insert_cands(v0, (unsigned)(i * 4), Klo, span, &lcnt, seg, ovf, &ctrl->ovf);
      insert_cands(v1, (unsigned)((i + stride) * 4), Klo, span, &lcnt, seg, ovf, &ctrl->ovf);
    }
  }
  for (; i < n4; i += stride) {
    uint4 v = x4[i];
    fx4 w;
    bool anyc = false;
    #pragma unroll
    for (int c = 0; c < 4; ++c) {
      unsigned raw = (&v.x)[c];
      unsigned key = raw & 0x7fffffffu;
      w[c] = (key >= Khi) ? __uint_as_float(raw) : 0.0f;
      below += (key < Klo) ? 1u : 0u;
      anyc |= (key - Klo) < span;
    }
    __builtin_nontemporal_store(w, (fx4*)&o4[i]);
    if (__ballot(anyc))
      insert_cands(v, (unsigned)(i * 4), Klo, span, &lcnt, seg, ovf, &ctrl->ovf);
  }
  for (long long t = n4 * 4 + (long long)blockIdx.x * blockDim.x + threadIdx.x; t < n; t += stride) {
    unsigned raw = xs[t];
    unsigned key = raw & 0x7fffffffu;
    os[t] = (key >= Khi) ? __uint_as_float(raw) : 0.0f;
    if (key < Klo) below++;
    else if (key < Khi) {
      unsigned pos = atomicAdd(&lcnt, 1u);
      uint2 e; e.x = raw; e.y = (unsigned)t;
      if (pos < SEGCAP) seg[pos] = e;
      else { unsigned op = atomicAdd(&ctrl->ovf, 1u); if (op < OCAP) ovf[op] = e; }
    }
  }
  for (int o = 32; o > 0; o >>= 1) below += __shfl_down(below, o, 64);
  if ((threadIdx.x & 63u) == 0u) wred[threadIdx.x >> 6] = below;
  __syncthreads();
  if (threadIdx.x == 0) {
    unsigned s = 0;
    for (int i2 = 0; i2 < 8; ++i2) s += wred[i2];
    atomicAdd(&ctrl->below, s);
    seg_cnt[blockIdx.x] = (lcnt < SEGCAP) ? lcnt : SEGCAP;
  }
}

// Candidate ulp-hist: h20[key - klo] via global atomics (~sparse hits).
__global__ __launch_bounds__(256) void cand20_k(
    const uint2* __restrict__ cand, const unsigned* __restrict__ seg_cnt,
    const Ctrl* __restrict__ ctrl, unsigned* __restrict__ h20)
{
  const unsigned klo = ctrl->klo;
  const uint2* __restrict__ seg = cand + (size_t)blockIdx.x * SEGCAP;
  unsigned cnt = seg_cnt[blockIdx.x];
  for (unsigned t = threadIdx.x; t < cnt; t += 256u) {
    unsigned idx = (seg[t].x & 0x7fffffffu) - klo;
    if (idx < (1u << 19)) atomicAdd(&h20[idx], 1u);
  }
  if (blockIdx.x == 0) {
    unsigned oc = ctrl->ovf; if (oc > OCAP) oc = OCAP;
    const uint2* __restrict__ ovf = cand + (size_t)SEGS * SEGCAP;
    for (unsigned t = threadIdx.x; t < oc; t += 256u) {
      unsigned idx = (ovf[t].x & 0x7fffffffu) - klo;
      if (idx < (1u << 19)) atomicAdd(&h20[idx], 1u);
    }
  }
}

// chunk sums (grid = nbins/1024 blocks).
__global__ __launch_bounds__(256) void scan_big1_k(
    const unsigned* __restrict__ hist, unsigned* __restrict__ chunkSums)
{
  __shared__ unsigned red[256];
  const unsigned base = blockIdx.x * 1024u;
  unsigned s = 0;
  for (unsigned i = threadIdx.x; i < 1024u; i += 256u) s += hist[base + i];
  red[threadIdx.x] = s;
  __syncthreads();
  for (unsigned off = 128; off > 0; off >>= 1) {
    if (threadIdx.x < off) red[threadIdx.x] += red[threadIdx.x + off];
    __syncthreads();
  }
  if (threadIdx.x == 0) chunkSums[blockIdx.x] = red[0];
}

// ulp-exact select + thr + invariant verification (+ lazy repair-hist zero).
__global__ __launch_bounds__(1024) void scan20_k(
    const unsigned* __restrict__ h20, const unsigned* __restrict__ cs,
    Ctrl* __restrict__ ctrl, unsigned k0,
    unsigned* __restrict__ h13r, unsigned* __restrict__ h18r)
{
  __shared__ unsigned csh[512];
  __shared__ unsigned sc[1024];
  __shared__ unsigned sel[3];
  __shared__ unsigned sh_key, sh_found, sh_bad;
  const unsigned t = threadIdx.x;
  if (t == 0) { sh_found = 0u; sh_bad = 0u; }
  if (t < 512) csh[t] = cs[t];
  __syncthreads();
  const unsigned klo = ctrl->klo, khi = ctrl->khi;
  const unsigned below = ctrl->below, ovf = ctrl->ovf;
  const unsigned range = khi - klo;
  const unsigned rc = k0 - below;     // may wrap; verified below
  if (t == 0) {
    unsigned run = 0, ci = 0, cb = 0;
    for (int i = 0; i < 512; ++i) {
      unsigned cnt = csh[i];
      if (rc >= run && rc < run + cnt) { ci = (unsigned)i; cb = run; }
      run += cnt;
    }
    sel[0] = ci; sel[1] = cb; sel[2] = run;   // run = total
  }
  __syncthreads();
  const unsigned ci = sel[0], cb = sel[1], total = sel[2];
  unsigned val = h20[ci * 1024u + t];
  sc[t] = val;
  __syncthreads();
  for (unsigned off = 1; off < 1024; off <<= 1) {
    unsigned add = (t >= off) ? sc[t - off] : 0u;
    __syncthreads();
    sc[t] += add;
    __syncthreads();
  }
  const unsigned incl = sc[t], excl = incl - val;
  const unsigned rr = rc - cb;
  if (val > 0 && rc < total && rr >= excl && rr < incl) {
    unsigned key = klo + ci * 1024u + t;
    sh_key = key; sh_found = 1u;
    if (key < klo + 4u || key + 4u >= khi) sh_bad = 1u;
  }
  __syncthreads();
  if (t == 0) {
    bool bad = (k0 < below) || (rc >= total) || (ovf > OCAP) ||
               (range > (1u << 19)) || (sh_found == 0u) || (sh_bad != 0u);
    if (!bad) {
      unsigned key = sh_key;
      float v = __uint_as_float(key);
      ctrl->thr = __fdiv_rn(__fmul_rn(v, 0.1f), 0.1f);
      ctrl->prefix = key;
      sel[0] = 0u;
    } else sel[0] = 1u;
  }
  __syncthreads();
  if (sel[0]) {
    for (unsigned i = t; i < 8192u; i += 1024u) h13r[i] = 0u;
    for (unsigned i = t; i < 262144u; i += 1024u) h18r[i] = 0u;
    __syncthreads();
    if (t == 0) ctrl->flag = 1u;
  }
}

// Scatter-fix surviving candidates (skipped when repair flagged).
__global__ __launch_bounds__(256) void fixup_k(
    const uint2* __restrict__ cand, const unsigned* __restrict__ seg_cnt,
    const Ctrl* __restrict__ ctrl, float* __restrict__ out)
{
  if (*(volatile const unsigned*)&ctrl->flag != 0u) return;
  const float thr = ctrl->thr;
  const uint2* __restrict__ seg = cand + (size_t)blockIdx.x * SEGCAP;
  unsigned cnt = seg_cnt[blockIdx.x];
  for (unsigned t = threadIdx.x; t < cnt; t += 256u) {
    uint2 e = seg[t];
    float v = __uint_as_float(e.x);
    if (fabsf(v) > thr) out[e.y] = v;
  }
  if (blockIdx.x == 0) {
    unsigned oc = ctrl->ovf; if (oc > OCAP) oc = OCAP;
    const uint2* __restrict__ ovf = cand + (size_t)SEGS * SEGCAP;
    for (unsigned t = threadIdx.x; t < oc; t += 256u) {
      uint2 e = ovf[t];
      float v = __uint_as_float(e.x);
      if (fabsf(v) > thr) out[e.y] = v;
    }
  }
}

// ---------------- gated repair chain (exactness guarantee) ----------------

__global__ __launch_bounds__(256) void r13_k(
    const uint4* __restrict__ x4, long long n4,
    const unsigned* __restrict__ xs, long long n,
    unsigned* __restrict__ h13r, const Ctrl* __restrict__ ctrl)
{
  if (*(volatile const unsigned*)&ctrl->flag == 0u) return;
  __shared__ unsigned lh[8192];
  for (unsigned i = threadIdx.x; i < 8192u; i += 256u) lh[i] = 0u;
  __syncthreads();
  const long long stride = (long long)gridDim.x * blockDim.x;
  for (long long i = (long long)blockIdx.x * blockDim.x + threadIdx.x; i < n4; i += stride) {
    uint4 v = x4[i];
    atomicAdd(&lh[(v.x & 0x7fffffffu) >> 18], 1u);
    atomicAdd(&lh[(v.y & 0x7fffffffu) >> 18], 1u);
    atomicAdd(&lh[(v.z & 0x7fffffffu) >> 18], 1u);
    atomicAdd(&lh[(v.w & 0x7fffffffu) >> 18], 1u);
  }
  for (long long t = n4 * 4 + (long long)blockIdx.x * blockDim.x + threadIdx.x; t < n; t += stride)
    atomicAdd(&lh[(xs[t] & 0x7fffffffu) >> 18], 1u);
  __syncthreads();
  for (unsigned j = threadIdx.x; j < 8192u; j += 256u) {
    unsigned s = lh[j];
    if (s) atomicAdd(&h13r[j], s);
  }
}

__global__ __launch_bounds__(1024) void rscan13_k(
    const unsigned* __restrict__ h, Ctrl* __restrict__ ctrl, unsigned k0)
{
  if (*(volatile const unsigned*)&ctrl->flag == 0u) return;
  __shared__ unsigned wsum[16], wbase[16];
  const unsigned t = threadIdx.x, lane = t & 63u, wid = t >> 6;
  const unsigned lo = t * 8u, hi = lo + 8u;
  unsigned s = 0;
  for (unsigned j = lo; j < hi; ++j) s += h[j];
  unsigned run = s;
  for (unsigned o = 1; o < 64; o <<= 1) {
    unsigned v = __shfl_up(run, o, 64);
    if (lane >= o) run += v;
  }
  if (lane == 63u) wsum[wid] = run;
  __syncthreads();
  if (t == 0) { unsigned acc = 0; for (int i = 0; i < 16; ++i) { wbase[i] = acc; acc += wsum[i]; } }
  __syncthreads();
  const unsigned base = wbase[wid] + run - s;
  if (s > 0 && k0 >= base && k0 < base + s) {
    unsigned c = base;
    for (unsigned j = lo; j < hi; ++j) {
      unsigned cnt = h[j];
      if (k0 < c + cnt) { ctrl->prefix = j; ctrl->rank = k0 - c; break; }
      c += cnt;
    }
  }
}

__global__ __launch_bounds__(256) void rh18_k(
    const uint4* __restrict__ x4, long long n4,
    const unsigned* __restrict__ xs, long long n,
    unsigned* __restrict__ h18r, const Ctrl* __restrict__ ctrl)
{
  if (*(volatile const unsigned*)&ctrl->flag == 0u) return;
  const unsigned prefix = ctrl->prefix;
  const long long stride = (long long)gridDim.x * blockDim.x;
  for (long long i = (long long)blockIdx.x * blockDim.x + threadIdx.x; i < n4; i += stride) {
    uint4 v = x4[i];
    unsigned a = v.x & 0x7fffffffu, b = v.y & 0x7fffffffu;
    unsigned c = v.z & 0x7fffffffu, d = v.w & 0x7fffffffu;
    if ((a >> 18) == prefix) atomicAdd(&h18r[a & 0x3ffffu], 1u);
    if ((b >> 18) == prefix) atomicAdd(&h18r[b & 0x3ffffu], 1u);
    if ((c >> 18) == prefix) atomicAdd(&h18r[c & 0x3ffffu], 1u);
    if ((d >> 18) == prefix) atomicAdd(&h18r[d & 0x3ffffu], 1u);
  }
  for (long long t = n4 * 4 + (long long)blockIdx.x * blockDim.x + threadIdx.x; t < n; t += stride) {
    unsigned u = xs[t] & 0x7fffffffu;
    if ((u >> 18) == prefix) atomicAdd(&h18r[u & 0x3ffffu], 1u);
  }
}

__global__ __launch_bounds__(1024) void rs18_k(
    const unsigned* __restrict__ h, Ctrl* __restrict__ ctrl)
{
  if (*(volatile const unsigned*)&ctrl->flag == 0u) return;
  __shared__ unsigned wsum[16], wbase[16];
  const unsigned t = threadIdx.x, lane = t & 63u, wid = t >> 6;
  const unsigned lo = t * 256u, hi = lo + 256u;
  const unsigned oldP = ctrl->prefix;
  const unsigned r = ctrl->rank;
  unsigned s = 0;
  for (unsigned j = lo; j < hi; ++j) s += h[j];
  unsigned run = s;
  for (unsigned o = 1; o < 64; o <<= 1) {
    unsigned v = __shfl_up(run, o, 64);
    if (lane >= o) run += v;
  }
  if (lane == 63u) wsum[wid] = run;
  __syncthreads();
  if (t == 0) { unsigned acc = 0; for (int i = 0; i < 16; ++i) { wbase[i] = acc; acc += wsum[i]; } }
  __syncthreads();
  const unsigned base = wbase[wid] + run - s;
  if (s > 0 && r >= base && r < base + s) {
    unsigned c = base;
    for (unsigned j = lo; j < hi; ++j) {
      unsigned cnt = h[j];
      if (r < c + cnt) {
        unsigned key = (oldP << 18) | j;
        float v = __uint_as_float(key);
        ctrl->thr = __fdiv_rn(__fmul_rn(v, 0.1f), 0.1f);
        ctrl->prefix = key;
        break;
      }
      c += cnt;
    }
  }
}

__global__ __launch_bounds__(256) void rmask_k(
    const float4* __restrict__ x4, float4* __restrict__ o4, long long n4,
    const float* __restrict__ xs, float* __restrict__ os, long long n,
    const Ctrl* __restrict__ ctrl)
{
  if (*(volatile const unsigned*)&ctrl->flag == 0u) return;
  const float thr = ctrl->thr;
  const long long stride = (long long)gridDim.x * blockDim.x;
  for (long long i = (long long)blockIdx.x * blockDim.x + threadIdx.x; i < n4; i += stride) {
    float4 v = x4[i];
    fx4 w;
    w[0] = (fabsf(v.x) <= thr) ? 0.0f : v.x;
    w[1] = (fabsf(v.y) <= thr) ? 0.0f : v.y;
    w[2] = (fabsf(v.z) <= thr) ? 0.0f : v.z;
    w[3] = (fabsf(v.w) <= thr) ? 0.0f : v.w;
    __builtin_nontemporal_store(w, (fx4*)&o4[i]);
  }
  for (long long t = n4 * 4 + (long long)blockIdx.x * blockDim.x + threadIdx.x; t < n; t += stride) {
    float v = xs[t];
    os[t] = (fabsf(v) <= thr) ? 0.0f : v;
  }
}

// ---------------- fallback path ----------------

__global__ __launch_bounds__(256) void zero_words_k(unsigned* __restrict__ p, long long nwords) {
  long long i = (long long)blockIdx.x * blockDim.x + threadIdx.x;
  long long s = (long long)gridDim.x * blockDim.x;
  for (; i < nwords; i += s) p[i] = 0u;
}

__global__ __launch_bounds__(64) void init_ctrl_k(Ctrl* c0, unsigned k0,
                                                  Ctrl* c1, unsigned k1) {
  if (threadIdx.x == 0 && blockIdx.x == 0) {
    c0->prefix = 0u; c0->rank = k0; c0->thr = 0.0f; c0->ovf = 0u;
    c1->prefix = 0u; c1->rank = k1; c1->thr = 0.0f; c1->ovf = 0u;
  }
}

__global__ __launch_bounds__(64) void combine_thr_k(Ctrl* a, const Ctrl* b,
                                                    float lw, float hw) {
  if (threadIdx.x == 0 && blockIdx.x == 0) {
    float v0 = __uint_as_float(a->prefix);
    float v1 = __uint_as_float(b->prefix);
    float tq = __fadd_rn(__fmul_rn(v0, lw), __fmul_rn(v1, hw));
    a->thr = __fdiv_rn(__fmul_rn(tq, 0.1f), 0.1f);
  }
}

__global__ __launch_bounds__(1024) void scan_stage_k(
    const unsigned* __restrict__ hist, int bits, Ctrl* __restrict__ ctrl)
{
  __shared__ unsigned wsum[16], wbase[16];
  const unsigned nb = 1u << bits;
  const unsigned per = (nb + 1023u) >> 10;
  const unsigned t = threadIdx.x, lane = t & 63u, wid = t >> 6;
  const unsigned lo = t * per;
  const unsigned hi = (lo + per < nb) ? (lo + per) : nb;
  const unsigned oldPrefix = ctrl->prefix;
  const unsigned r = ctrl->rank;
  unsigned s = 0;
  for (unsigned j = lo; j < hi; ++j) s += hist[j];
  unsigned run = s;
  for (unsigned o = 1; o < 64; o <<= 1) {
    unsigned v = __shfl_up(run, o, 64);
    if (lane >= o) run += v;
  }
  if (lane == 63u) wsum[wid] = run;
  __syncthreads();
  if (t == 0) { unsigned acc = 0; for (int i = 0; i < 16; ++i) { wbase[i] = acc; acc += wsum[i]; } }
  __syncthreads();
  const unsigned base = wbase[wid] + run - s;
  if (s > 0 && r >= base && r < base + s) {
    unsigned c = base;
    for (unsigned j = lo; j < hi; ++j) {
      unsigned cnt = hist[j];
      if (r < c + cnt) {
        ctrl->prefix = (oldPrefix << bits) | j;
        ctrl->rank = r - c;
        break;
      }
      c += cnt;
    }
  }
}

__global__ __launch_bounds__(256) void hist_stage_k(
    const uint4* __restrict__ x4, long long n4,
    const unsigned* __restrict__ xs, long long n,
    unsigned* __restrict__ hist,
    const Ctrl* __restrict__ ctrl,
    int shift, int bits)
{
  __shared__ unsigned lh[4096];
  const unsigned nb = 1u << bits;
  const bool lds = (bits <= 12);
  if (lds) {
    for (unsigned i = threadIdx.x; i < nb; i += blockDim.x) lh[i] = 0u;
    __syncthreads();
  }
  const unsigned prefix = ctrl->prefix;
  const int top = shift + bits;
  const unsigned m = nb - 1u;
  const long long stride = (long long)gridDim.x * blockDim.x;
  long long i = (long long)blockIdx.x * blockDim.x + threadIdx.x;
  for (; i < n4; i += stride) {
    uint4 v = x4[i];
    unsigned a = v.x & 0x7fffffffu;
    unsigned b = v.y & 0x7fffffffu;
    unsigned c = v.z & 0x7fffffffu;
    unsigned d = v.w & 0x7fffffffu;
    if (lds) {
      if ((a >> top) == prefix) atomicAdd(&lh[(a >> shift) & m], 1u);
      if ((b >> top) == prefix) atomicAdd(&lh[(b >> shift) & m], 1u);
      if ((c >> top) == prefix) atomicAdd(&lh[(c >> shift) & m], 1u);
      if ((d >> top) == prefix) atomicAdd(&lh[(d >> shift) & m], 1u);
    } else {
      if ((a >> top) == prefix) atomicAdd(&hist[(a >> shift) & m], 1u);
      if ((b >> top) == prefix) atomicAdd(&hist[(b >> shift) & m], 1u);
      if ((c >> top) == prefix) atomicAdd(&hist[(c >> shift) & m], 1u);
      if ((d >> top) == prefix) atomicAdd(&hist[(d >> shift) & m], 1u);
    }
  }
  long long t = n4 * 4 + (long long)blockIdx.x * blockDim.x + threadIdx.x;
  for (; t < n; t += stride) {
    unsigned u = xs[t] & 0x7fffffffu;
    if ((u >> top) == prefix) {
      if (lds) atomicAdd(&lh[(u >> shift) & m], 1u);
      else     atomicAdd(&hist[(u >> shift) & m], 1u);
    }
  }
  if (lds) {
    __syncthreads();
    for (unsigned j = threadIdx.x; j < nb; j += blockDim.x) {
      unsigned cv = lh[j];
      if (cv) atomicAdd(&hist[j], cv);
    }
  }
}

__global__ __launch_bounds__(1024) void scan_big2_k(
    const unsigned* __restrict__ hist, const unsigned* __restrict__ chunkSums,
    Ctrl* __restrict__ ctrl)
{
  __shared__ unsigned cs[512];
  __shared__ unsigned sc[1024];
  __shared__ unsigned sel[2];
  const unsigned t = threadIdx.x;
  const unsigned oldPrefix = ctrl->prefix;
  const unsigned r = ctrl->rank;
  if (t < 512) cs[t] = chunkSums[t];
  __syncthreads();
  if (t == 0) {
    unsigned run = 0, ci = 0, cb = 0;
    for (int i = 0; i < 512; ++i) {
      unsigned cnt = cs[i];
      if (r >= run && r < run + cnt) { ci = (unsigned)i; cb = run; }
      run += cnt;
    }
    sel[0] = ci; sel[1] = cb;
  }
  __syncthreads();
  const unsigned ci = sel[0], cb = sel[1];
  const unsigned val = hist[ci * 1024u + t];
  sc[t] = val;
  __syncthreads();
  for (unsigned off = 1; off < 1024; off <<= 1) {
    unsigned add = (t >= off) ? sc[t - off] : 0u;
    __syncthreads();
    sc[t] += add;
    __syncthreads();
  }
  const unsigned incl = sc[t];
  const unsigned excl = incl - val;
  const unsigned rr = r - cb;
  if (val > 0 && rr >= excl && rr < incl) {
    ctrl->prefix = (oldPrefix << 19) | (ci * 1024u + t);
    ctrl->rank = rr - excl;
  }
}

__global__ __launch_bounds__(256) void mask_k(
    const float4* __restrict__ x4, float4* __restrict__ o4, long long n4,
    const float* __restrict__ xs, float* __restrict__ os, long long n,
    const Ctrl* __restrict__ ctrl)
{
  const float thr = ctrl->thr;
  const long long stride = (long long)gridDim.x * blockDim.x;
  long long i = (long long)blockIdx.x * blockDim.x + threadIdx.x;
  for (; i < n4; i += stride) {
    float4 v = x4[i];
    float4 w;
    w.x = (fabsf(v.x) <= thr) ? 0.0f : v.x;
    w.y = (fabsf(v.y) <= thr) ? 0.0f : v.y;
    w.z = (fabsf(v.z) <= thr) ? 0.0f : v.z;
    w.w = (fabsf(v.w) <= thr) ? 0.0f : v.w;
    o4[i] = w;
  }
  long long t = n4 * 4 + (long long)blockIdx.x * blockDim.x + threadIdx.x;
  for (; t < n; t += stride) {
    float v = xs[t];
    os[t] = (fabsf(v) <= thr) ? 0.0f : v;
  }
}

// ---------------- launch ----------------

extern "C" void kernel_launch(void* const* d_in, const int* in_sizes, int n_in,
                              void* d_out, int out_size, void* d_ws, size_t ws_size,
                              hipStream_t stream)
{
  const float* x = (const float*)d_in[0];
  const long long N = (long long)in_sizes[0];
  const long long n4 = N >> 2;
  const uint4* x4 = (const uint4*)x;
  const unsigned* xbits = (const unsigned*)x;

  // jnp.quantile fp32 index math: idx = 0.5f * f32(N-1).
  float idxf = 0.5f * (float)(N - 1);
  float lowf = floorf(idxf);
  float highf = ceilf(idxf);
  float hw = idxf - lowf;
  float lw = 1.0f - hw;
  unsigned k0 = (unsigned)lowf;
  unsigned k1 = (unsigned)highf;
  int dual = (hw != 0.0f);
  if (!dual) k1 = k0;

  const size_t needC = CAND_BYTE_OFF + ((size_t)SEGS * SEGCAP + OCAP) * 8;  // ~21 MB

  if (!dual && N < (1ll << 32) && n4 >= (1ll << 20) && ws_size >= needC) {
    unsigned* arena = (unsigned*)d_ws;
    Ctrl* c0 = (Ctrl*)arena;
    unsigned* seg_cnt   = arena + W_SEGCNT;
    unsigned* chunkSums = arena + W_CHUNK;
    unsigned* h20       = arena + W_H20;
    unsigned* h13r      = arena + W_H13R;
    unsigned* h18r      = arena + W_H18R;
    uint2* cand = (uint2*)((char*)d_ws + CAND_BYTE_OFF);

    // Guessed candidate interval around median(|N(0,1)|)=0.674490.
    // Empirical-median sigma at N=90M is ~8.3e-5, so [0.6740,0.6750) gives
    // >=6-sigma margins with only ~57K candidates. Pure performance hint:
    // scan20 verifies exact invariants; gated repair recomputes on any miss.
    float flo = 0.6740f, fhi = 0.6750f;
    unsigned Klo, Khi;
    memcpy(&Klo, &flo, 4);
    memcpy(&Khi, &fhi, 4);

    setup_k<<<1, 64, 0, stream>>>(arena, k0, Klo, Khi);
    mega_k<<<MB, MT, 0, stream>>>(x4, (float4*)d_out, n4, xbits, (float*)d_out, N,
                                  arena, cand);
    cand20_k<<<SEGS, 256, 0, stream>>>(cand, seg_cnt, c0, h20);
    scan_big1_k<<<512, 256, 0, stream>>>(h20, chunkSums);
    scan20_k<<<1, 1024, 0, stream>>>(h20, chunkSums, c0, k0, h13r, h18r);
    fixup_k<<<SEGS, 256, 0, stream>>>(cand, seg_cnt, c0, (float*)d_out);
    // gated repair chain (early-exit when flag==0)
    r13_k<<<1024, 256, 0, stream>>>(x4, n4, xbits, N, h13r, c0);
    rscan13_k<<<1, 1024, 0, stream>>>(h13r, c0, k0);
    rh18_k<<<1024, 256, 0, stream>>>(x4, n4, xbits, N, h18r, c0);
    rs18_k<<<1, 1024, 0, stream>>>(h18r, c0);
    rmask_k<<<1024, 256, 0, stream>>>((const float4*)x, (float4*)d_out, n4,
                                      x, (float*)d_out, N, c0);
    return;
  }

  // ---------- fallback: two-full-hist structure with kernel zeroing ----------
  const size_t needA = 65536 + (size_t)(1u << 19) * 4;  // 2,162,688
  char* wsb = (char*)d_ws;
  char* arena = (ws_size >= needA) ? wsb : (char*)d_out;  // d_out fully rewritten at end
  Ctrl* c0 = (ws_size >= 128) ? (Ctrl*)wsb : (Ctrl*)arena;
  Ctrl* c1 = c0 + 1;
  unsigned* chunkSums = (unsigned*)(arena + 128);
  unsigned* h1 = (unsigned*)(arena + 4096);
  unsigned* h2 = (unsigned*)(arena + 65536);
  const long long zwords = (long long)(needA - 4096) / 4;

  zero_words_k<<<512, 256, 0, stream>>>((unsigned*)(arena + 4096), zwords);
  init_ctrl_k<<<1, 64, 0, stream>>>(c0, k0, (dual ? c1 : c0), k1);

  const int nchain = dual ? 2 : 1;
  for (int chain = 0; chain < nchain; ++chain) {
    Ctrl* cc = chain ? c1 : c0;
    if (chain) zero_words_k<<<512, 256, 0, stream>>>((unsigned*)(arena + 4096), zwords);
    hist_stage_k<<<2048, 256, 0, stream>>>(x4, n4, xbits, N, h1, cc, 19, 12);
    scan_stage_k<<<1, 1024, 0, stream>>>(h1, 12, cc);
    hist_stage_k<<<2048, 256, 0, stream>>>(x4, n4, xbits, N, h2, cc, 0, 19);
    scan_big1_k<<<512, 256, 0, stream>>>(h2, chunkSums);
    scan_big2_k<<<1, 1024, 0, stream>>>(h2, chunkSums, cc);
  }
  combine_thr_k<<<1, 64, 0, stream>>>(c0, (dual ? c1 : c0), lw, hw);
  mask_k<<<2048, 256, 0, stream>>>((const float4*)x, (float4*)d_out, n4,
                                   x, (float*)d_out, N, c0);
}

// Round 16
// 182.453 us; speedup vs baseline: 1.0538x; 1.0191x over previous
//
#include <hip/hip_runtime.h>
#include <stdint.h>
#include <string.h>

// Exact global median-of-|x| + masked copy, one full-data pass.
// thr replicates jnp fp32 semantics: thr = (t*0.1f)/0.1f (RN).
//
// PROVEN round-12 configuration (183.2us, absmax 0) — reverted after R15's
// fused-histogram race. Ballot-gated candidate path; nt stores; narrow
// guessed interval [0.6740,0.6750) (~57K candidates). Exactness
// unconditional: scan20 verifies all invariants and the gated repair chain
// recomputes from scratch on any miss.

struct Ctrl {
  unsigned prefix, rank;
  float    thr;
  unsigned ovf, below, blo, bhi, flag;
  unsigned klo, khi, kloA, khiA, s2, cblo, pad0, pad1;
};

typedef float fx4 __attribute__((ext_vector_type(4)));

#define SEGS   1024u
#define SEGCAP 2048u
#define OCAP   131072u
#define MB     1024u
#define MT     512u

// Arena word offsets:
#define W_SEGCNT 32u        // seg_cnt (1024)
#define W_CHUNK  1056u      // chunkSums (512)
#define W_H20    4096u      // ulp hist (2^19)      [zeroed by mega]
#define W_H13R   528384u    // repair 13-bit (8192) [zeroed by scan20 on flag]
#define W_H18R   536576u    // repair 18-bit (262144)[zeroed by scan20 on flag]
#define CAND_BYTE_OFF 4194304u

// ---------------- fast path ----------------

__global__ __launch_bounds__(64) void setup_k(unsigned* arena, unsigned k0,
                                              unsigned Klo, unsigned Khi) {
  if (threadIdx.x == 0 && blockIdx.x == 0) {
    Ctrl* c = (Ctrl*)arena;
    c->prefix = 0u; c->rank = k0; c->thr = 0.0f;
    c->ovf = 0u; c->below = 0u; c->blo = 0u; c->bhi = 0u; c->flag = 0u;
    c->klo = Klo; c->khi = Khi;
    c->kloA = 0u; c->khiA = 0u; c->s2 = 0u; c->cblo = 0u;
  }
}

// The single full pass: zero h20, classify, count below, compact candidates.
// Hot loop is load->classify->store; candidate insertion is ballot-gated.
__global__ __launch_bounds__(MT) void mega_k(
    const uint4* __restrict__ x4, float4* __restrict__ o4, long long n4,
    const unsigned* __restrict__ xs, float* __restrict__ os, long long n,
    unsigned* __restrict__ arena, uint2* __restrict__ cand)
{
  __shared__ unsigned lcnt;
  __shared__ unsigned wred[8];
  Ctrl* ctrl = (Ctrl*)arena;
  unsigned* seg_cnt = arena + W_SEGCNT;
  unsigned* h20 = arena + W_H20;
  // zero h20 (exactly 1 word per thread: MB*MT = 2^19)
  {
    unsigned i = blockIdx.x * MT + threadIdx.x;
    if (i < (1u << 19)) h20[i] = 0u;
  }
  if (threadIdx.x == 0) lcnt = 0u;
  __syncthreads();
  const unsigned Klo = ctrl->klo, Khi = ctrl->khi;
  const unsigned span = Khi - Klo;
  uint2* __restrict__ seg = cand + (size_t)blockIdx.x * SEGCAP;
  uint2* __restrict__ ovf = cand + (size_t)SEGS * SEGCAP;
  unsigned below = 0;
  const long long stride = (long long)gridDim.x * blockDim.x;
  for (long long i = (long long)blockIdx.x * blockDim.x + threadIdx.x; i < n4; i += stride) {
    uint4 v = x4[i];
    fx4 w;
    bool anyc = false;
    #pragma unroll
    for (int c = 0; c < 4; ++c) {
      unsigned raw = (&v.x)[c];
      unsigned key = raw & 0x7fffffffu;
      w[c] = (key >= Khi) ? __uint_as_float(raw) : 0.0f;
      below += (key < Klo) ? 1u : 0u;
      anyc |= (key - Klo) < span;      // key in [Klo,Khi), unsigned trick
    }
    __builtin_nontemporal_store(w, (fx4*)&o4[i]);
    if (__ballot(anyc)) {              // wave-uniform, almost always false
      unsigned bidx = (unsigned)(i * 4);
      #pragma unroll
      for (int c = 0; c < 4; ++c) {
        unsigned raw = (&v.x)[c];
        unsigned key = raw & 0x7fffffffu;
        if ((key - Klo) < span) {
          unsigned pos = atomicAdd(&lcnt, 1u);
          uint2 e; e.x = raw; e.y = bidx + (unsigned)c;
          if (pos < SEGCAP) seg[pos] = e;
          else { unsigned op = atomicAdd(&ctrl->ovf, 1u); if (op < OCAP) ovf[op] = e; }
        }
      }
    }
  }
  for (long long t = n4 * 4 + (long long)blockIdx.x * blockDim.x + threadIdx.x; t < n; t += stride) {
    unsigned raw = xs[t];
    unsigned key = raw & 0x7fffffffu;
    os[t] = (key >= Khi) ? __uint_as_float(raw) : 0.0f;
    if (key < Klo) below++;
    else if (key < Khi) {
      unsigned pos = atomicAdd(&lcnt, 1u);
      uint2 e; e.x = raw; e.y = (unsigned)t;
      if (pos < SEGCAP) seg[pos] = e;
      else { unsigned op = atomicAdd(&ctrl->ovf, 1u); if (op < OCAP) ovf[op] = e; }
    }
  }
  for (int o = 32; o > 0; o >>= 1) below += __shfl_down(below, o, 64);
  if ((threadIdx.x & 63u) == 0u) wred[threadIdx.x >> 6] = below;
  __syncthreads();
  if (threadIdx.x == 0) {
    unsigned s = 0;
    for (int i = 0; i < 8; ++i) s += wred[i];
    atomicAdd(&ctrl->below, s);
    seg_cnt[blockIdx.x] = (lcnt < SEGCAP) ? lcnt : SEGCAP;
  }
}

// Candidate ulp-hist: h20[key - klo] via global atomics (~sparse hits).
__global__ __launch_bounds__(256) void cand20_k(
    const uint2* __restrict__ cand, const unsigned* __restrict__ seg_cnt,
    const Ctrl* __restrict__ ctrl, unsigned* __restrict__ h20)
{
  const unsigned klo = ctrl->klo;
  const uint2* __restrict__ seg = cand + (size_t)blockIdx.x * SEGCAP;
  unsigned cnt = seg_cnt[blockIdx.x];
  for (unsigned t = threadIdx.x; t < cnt; t += 256u) {
    unsigned idx = (seg[t].x & 0x7fffffffu) - klo;
    if (idx < (1u << 19)) atomicAdd(&h20[idx], 1u);
  }
  if (blockIdx.x == 0) {
    unsigned oc = ctrl->ovf; if (oc > OCAP) oc = OCAP;
    const uint2* __restrict__ ovf = cand + (size_t)SEGS * SEGCAP;
    for (unsigned t = threadIdx.x; t < oc; t += 256u) {
      unsigned idx = (ovf[t].x & 0x7fffffffu) - klo;
      if (idx < (1u << 19)) atomicAdd(&h20[idx], 1u);
    }
  }
}

// chunk sums (grid = nbins/1024 blocks).
__global__ __launch_bounds__(256) void scan_big1_k(
    const unsigned* __restrict__ hist, unsigned* __restrict__ chunkSums)
{
  __shared__ unsigned red[256];
  const unsigned base = blockIdx.x * 1024u;
  unsigned s = 0;
  for (unsigned i = threadIdx.x; i < 1024u; i += 256u) s += hist[base + i];
  red[threadIdx.x] = s;
  __syncthreads();
  for (unsigned off = 128; off > 0; off >>= 1) {
    if (threadIdx.x < off) red[threadIdx.x] += red[threadIdx.x + off];
    __syncthreads();
  }
  if (threadIdx.x == 0) chunkSums[blockIdx.x] = red[0];
}

// ulp-exact select + thr + invariant verification (+ lazy repair-hist zero).
__global__ __launch_bounds__(1024) void scan20_k(
    const unsigned* __restrict__ h20, const unsigned* __restrict__ cs,
    Ctrl* __restrict__ ctrl, unsigned k0,
    unsigned* __restrict__ h13r, unsigned* __restrict__ h18r)
{
  __shared__ unsigned csh[512];
  __shared__ unsigned sc[1024];
  __shared__ unsigned sel[3];
  __shared__ unsigned sh_key, sh_found, sh_bad;
  const unsigned t = threadIdx.x;
  if (t == 0) { sh_found = 0u; sh_bad = 0u; }
  if (t < 512) csh[t] = cs[t];
  __syncthreads();
  const unsigned klo = ctrl->klo, khi = ctrl->khi;
  const unsigned below = ctrl->below, ovf = ctrl->ovf;
  const unsigned range = khi - klo;
  const unsigned rc = k0 - below;     // may wrap; verified below
  if (t == 0) {
    unsigned run = 0, ci = 0, cb = 0;
    for (int i = 0; i < 512; ++i) {
      unsigned cnt = csh[i];
      if (rc >= run && rc < run + cnt) { ci = (unsigned)i; cb = run; }
      run += cnt;
    }
    sel[0] = ci; sel[1] = cb; sel[2] = run;   // run = total
  }
  __syncthreads();
  const unsigned ci = sel[0], cb = sel[1], total = sel[2];
  unsigned val = h20[ci * 1024u + t];
  sc[t] = val;
  __syncthreads();
  for (unsigned off = 1; off < 1024; off <<= 1) {
    unsigned add = (t >= off) ? sc[t - off] : 0u;
    __syncthreads();
    sc[t] += add;
    __syncthreads();
  }
  const unsigned incl = sc[t], excl = incl - val;
  const unsigned rr = rc - cb;
  if (val > 0 && rc < total && rr >= excl && rr < incl) {
    unsigned key = klo + ci * 1024u + t;
    sh_key = key; sh_found = 1u;
    if (key < klo + 4u || key + 4u >= khi) sh_bad = 1u;
  }
  __syncthreads();
  if (t == 0) {
    bool bad = (k0 < below) || (rc >= total) || (ovf > OCAP) ||
               (range > (1u << 19)) || (sh_found == 0u) || (sh_bad != 0u);
    if (!bad) {
      unsigned key = sh_key;
      float v = __uint_as_float(key);
      ctrl->thr = __fdiv_rn(__fmul_rn(v, 0.1f), 0.1f);
      ctrl->prefix = key;
      sel[0] = 0u;
    } else sel[0] = 1u;
  }
  __syncthreads();
  if (sel[0]) {
    for (unsigned i = t; i < 8192u; i += 1024u) h13r[i] = 0u;
    for (unsigned i = t; i < 262144u; i += 1024u) h18r[i] = 0u;
    __syncthreads();
    if (t == 0) ctrl->flag = 1u;
  }
}

// Scatter-fix surviving candidates (skipped when repair flagged).
__global__ __launch_bounds__(256) void fixup_k(
    const uint2* __restrict__ cand, const unsigned* __restrict__ seg_cnt,
    const Ctrl* __restrict__ ctrl, float* __restrict__ out)
{
  if (*(volatile const unsigned*)&ctrl->flag != 0u) return;
  const float thr = ctrl->thr;
  const uint2* __restrict__ seg = cand + (size_t)blockIdx.x * SEGCAP;
  unsigned cnt = seg_cnt[blockIdx.x];
  for (unsigned t = threadIdx.x; t < cnt; t += 256u) {
    uint2 e = seg[t];
    float v = __uint_as_float(e.x);
    if (fabsf(v) > thr) out[e.y] = v;
  }
  if (blockIdx.x == 0) {
    unsigned oc = ctrl->ovf; if (oc > OCAP) oc = OCAP;
    const uint2* __restrict__ ovf = cand + (size_t)SEGS * SEGCAP;
    for (unsigned t = threadIdx.x; t < oc; t += 256u) {
      uint2 e = ovf[t];
      float v = __uint_as_float(e.x);
      if (fabsf(v) > thr) out[e.y] = v;
    }
  }
}

// ---------------- gated repair chain (exactness guarantee) ----------------

__global__ __launch_bounds__(256) void r13_k(
    const uint4* __restrict__ x4, long long n4,
    const unsigned* __restrict__ xs, long long n,
    unsigned* __restrict__ h13r, const Ctrl* __restrict__ ctrl)
{
  if (*(volatile const unsigned*)&ctrl->flag == 0u) return;
  __shared__ unsigned lh[8192];
  for (unsigned i = threadIdx.x; i < 8192u; i += 256u) lh[i] = 0u;
  __syncthreads();
  const long long stride = (long long)gridDim.x * blockDim.x;
  for (long long i = (long long)blockIdx.x * blockDim.x + threadIdx.x; i < n4; i += stride) {
    uint4 v = x4[i];
    atomicAdd(&lh[(v.x & 0x7fffffffu) >> 18], 1u);
    atomicAdd(&lh[(v.y & 0x7fffffffu) >> 18], 1u);
    atomicAdd(&lh[(v.z & 0x7fffffffu) >> 18], 1u);
    atomicAdd(&lh[(v.w & 0x7fffffffu) >> 18], 1u);
  }
  for (long long t = n4 * 4 + (long long)blockIdx.x * blockDim.x + threadIdx.x; t < n; t += stride)
    atomicAdd(&lh[(xs[t] & 0x7fffffffu) >> 18], 1u);
  __syncthreads();
  for (unsigned j = threadIdx.x; j < 8192u; j += 256u) {
    unsigned s = lh[j];
    if (s) atomicAdd(&h13r[j], s);
  }
}

__global__ __launch_bounds__(1024) void rscan13_k(
    const unsigned* __restrict__ h, Ctrl* __restrict__ ctrl, unsigned k0)
{
  if (*(volatile const unsigned*)&ctrl->flag == 0u) return;
  __shared__ unsigned wsum[16], wbase[16];
  const unsigned t = threadIdx.x, lane = t & 63u, wid = t >> 6;
  const unsigned lo = t * 8u, hi = lo + 8u;
  unsigned s = 0;
  for (unsigned j = lo; j < hi; ++j) s += h[j];
  unsigned run = s;
  for (unsigned o = 1; o < 64; o <<= 1) {
    unsigned v = __shfl_up(run, o, 64);
    if (lane >= o) run += v;
  }
  if (lane == 63u) wsum[wid] = run;
  __syncthreads();
  if (t == 0) { unsigned acc = 0; for (int i = 0; i < 16; ++i) { wbase[i] = acc; acc += wsum[i]; } }
  __syncthreads();
  const unsigned base = wbase[wid] + run - s;
  if (s > 0 && k0 >= base && k0 < base + s) {
    unsigned c = base;
    for (unsigned j = lo; j < hi; ++j) {
      unsigned cnt = h[j];
      if (k0 < c + cnt) { ctrl->prefix = j; ctrl->rank = k0 - c; break; }
      c += cnt;
    }
  }
}

__global__ __launch_bounds__(256) void rh18_k(
    const uint4* __restrict__ x4, long long n4,
    const unsigned* __restrict__ xs, long long n,
    unsigned* __restrict__ h18r, const Ctrl* __restrict__ ctrl)
{
  if (*(volatile const unsigned*)&ctrl->flag == 0u) return;
  const unsigned prefix = ctrl->prefix;
  const long long stride = (long long)gridDim.x * blockDim.x;
  for (long long i = (long long)blockIdx.x * blockDim.x + threadIdx.x; i < n4; i += stride) {
    uint4 v = x4[i];
    unsigned a = v.x & 0x7fffffffu, b = v.y & 0x7fffffffu;
    unsigned c = v.z & 0x7fffffffu, d = v.w & 0x7fffffffu;
    if ((a >> 18) == prefix) atomicAdd(&h18r[a & 0x3ffffu], 1u);
    if ((b >> 18) == prefix) atomicAdd(&h18r[b & 0x3ffffu], 1u);
    if ((c >> 18) == prefix) atomicAdd(&h18r[c & 0x3ffffu], 1u);
    if ((d >> 18) == prefix) atomicAdd(&h18r[d & 0x3ffffu], 1u);
  }
  for (long long t = n4 * 4 + (long long)blockIdx.x * blockDim.x + threadIdx.x; t < n; t += stride) {
    unsigned u = xs[t] & 0x7fffffffu;
    if ((u >> 18) == prefix) atomicAdd(&h18r[u & 0x3ffffu], 1u);
  }
}

__global__ __launch_bounds__(1024) void rs18_k(
    const unsigned* __restrict__ h, Ctrl* __restrict__ ctrl)
{
  if (*(volatile const unsigned*)&ctrl->flag == 0u) return;
  __shared__ unsigned wsum[16], wbase[16];
  const unsigned t = threadIdx.x, lane = t & 63u, wid = t >> 6;
  const unsigned lo = t * 256u, hi = lo + 256u;
  const unsigned oldP = ctrl->prefix;
  const unsigned r = ctrl->rank;
  unsigned s = 0;
  for (unsigned j = lo; j < hi; ++j) s += h[j];
  unsigned run = s;
  for (unsigned o = 1; o < 64; o <<= 1) {
    unsigned v = __shfl_up(run, o, 64);
    if (lane >= o) run += v;
  }
  if (lane == 63u) wsum[wid] = run;
  __syncthreads();
  if (t == 0) { unsigned acc = 0; for (int i = 0; i < 16; ++i) { wbase[i] = acc; acc += wsum[i]; } }
  __syncthreads();
  const unsigned base = wbase[wid] + run - s;
  if (s > 0 && r >= base && r < base + s) {
    unsigned c = base;
    for (unsigned j = lo; j < hi; ++j) {
      unsigned cnt = h[j];
      if (r < c + cnt) {
        unsigned key = (oldP << 18) | j;
        float v = __uint_as_float(key);
        ctrl->thr = __fdiv_rn(__fmul_rn(v, 0.1f), 0.1f);
        ctrl->prefix = key;
        break;
      }
      c += cnt;
    }
  }
}

__global__ __launch_bounds__(256) void rmask_k(
    const float4* __restrict__ x4, float4* __restrict__ o4, long long n4,
    const float* __restrict__ xs, float* __restrict__ os, long long n,
    const Ctrl* __restrict__ ctrl)
{
  if (*(volatile const unsigned*)&ctrl->flag == 0u) return;
  const float thr = ctrl->thr;
  const long long stride = (long long)gridDim.x * blockDim.x;
  for (long long i = (long long)blockIdx.x * blockDim.x + threadIdx.x; i < n4; i += stride) {
    float4 v = x4[i];
    fx4 w;
    w[0] = (fabsf(v.x) <= thr) ? 0.0f : v.x;
    w[1] = (fabsf(v.y) <= thr) ? 0.0f : v.y;
    w[2] = (fabsf(v.z) <= thr) ? 0.0f : v.z;
    w[3] = (fabsf(v.w) <= thr) ? 0.0f : v.w;
    __builtin_nontemporal_store(w, (fx4*)&o4[i]);
  }
  for (long long t = n4 * 4 + (long long)blockIdx.x * blockDim.x + threadIdx.x; t < n; t += stride) {
    float v = xs[t];
    os[t] = (fabsf(v) <= thr) ? 0.0f : v;
  }
}

// ---------------- fallback path ----------------

__global__ __launch_bounds__(256) void zero_words_k(unsigned* __restrict__ p, long long nwords) {
  long long i = (long long)blockIdx.x * blockDim.x + threadIdx.x;
  long long s = (long long)gridDim.x * blockDim.x;
  for (; i < nwords; i += s) p[i] = 0u;
}

__global__ __launch_bounds__(64) void init_ctrl_k(Ctrl* c0, unsigned k0,
                                                  Ctrl* c1, unsigned k1) {
  if (threadIdx.x == 0 && blockIdx.x == 0) {
    c0->prefix = 0u; c0->rank = k0; c0->thr = 0.0f; c0->ovf = 0u;
    c1->prefix = 0u; c1->rank = k1; c1->thr = 0.0f; c1->ovf = 0u;
  }
}

__global__ __launch_bounds__(64) void combine_thr_k(Ctrl* a, const Ctrl* b,
                                                    float lw, float hw) {
  if (threadIdx.x == 0 && blockIdx.x == 0) {
    float v0 = __uint_as_float(a->prefix);
    float v1 = __uint_as_float(b->prefix);
    float tq = __fadd_rn(__fmul_rn(v0, lw), __fmul_rn(v1, hw));
    a->thr = __fdiv_rn(__fmul_rn(tq, 0.1f), 0.1f);
  }
}

__global__ __launch_bounds__(1024) void scan_stage_k(
    const unsigned* __restrict__ hist, int bits, Ctrl* __restrict__ ctrl)
{
  __shared__ unsigned wsum[16], wbase[16];
  const unsigned nb = 1u << bits;
  const unsigned per = (nb + 1023u) >> 10;
  const unsigned t = threadIdx.x, lane = t & 63u, wid = t >> 6;
  const unsigned lo = t * per;
  const unsigned hi = (lo + per < nb) ? (lo + per) : nb;
  const unsigned oldPrefix = ctrl->prefix;
  const unsigned r = ctrl->rank;
  unsigned s = 0;
  for (unsigned j = lo; j < hi; ++j) s += hist[j];
  unsigned run = s;
  for (unsigned o = 1; o < 64; o <<= 1) {
    unsigned v = __shfl_up(run, o, 64);
    if (lane >= o) run += v;
  }
  if (lane == 63u) wsum[wid] = run;
  __syncthreads();
  if (t == 0) { unsigned acc = 0; for (int i = 0; i < 16; ++i) { wbase[i] = acc; acc += wsum[i]; } }
  __syncthreads();
  const unsigned base = wbase[wid] + run - s;
  if (s > 0 && r >= base && r < base + s) {
    unsigned c = base;
    for (unsigned j = lo; j < hi; ++j) {
      unsigned cnt = hist[j];
      if (r < c + cnt) {
        ctrl->prefix = (oldPrefix << bits) | j;
        ctrl->rank = r - c;
        break;
      }
      c += cnt;
    }
  }
}

__global__ __launch_bounds__(256) void hist_stage_k(
    const uint4* __restrict__ x4, long long n4,
    const unsigned* __restrict__ xs, long long n,
    unsigned* __restrict__ hist,
    const Ctrl* __restrict__ ctrl,
    int shift, int bits)
{
  __shared__ unsigned lh[4096];
  const unsigned nb = 1u << bits;
  const bool lds = (bits <= 12);
  if (lds) {
    for (unsigned i = threadIdx.x; i < nb; i += blockDim.x) lh[i] = 0u;
    __syncthreads();
  }
  const unsigned prefix = ctrl->prefix;
  const int top = shift + bits;
  const unsigned m = nb - 1u;
  const long long stride = (long long)gridDim.x * blockDim.x;
  long long i = (long long)blockIdx.x * blockDim.x + threadIdx.x;
  for (; i < n4; i += stride) {
    uint4 v = x4[i];
    unsigned a = v.x & 0x7fffffffu;
    unsigned b = v.y & 0x7fffffffu;
    unsigned c = v.z & 0x7fffffffu;
    unsigned d = v.w & 0x7fffffffu;
    if (lds) {
      if ((a >> top) == prefix) atomicAdd(&lh[(a >> shift) & m], 1u);
      if ((b >> top) == prefix) atomicAdd(&lh[(b >> shift) & m], 1u);
      if ((c >> top) == prefix) atomicAdd(&lh[(c >> shift) & m], 1u);
      if ((d >> top) == prefix) atomicAdd(&lh[(d >> shift) & m], 1u);
    } else {
      if ((a >> top) == prefix) atomicAdd(&hist[(a >> shift) & m], 1u);
      if ((b >> top) == prefix) atomicAdd(&hist[(b >> shift) & m], 1u);
      if ((c >> top) == prefix) atomicAdd(&hist[(c >> shift) & m], 1u);
      if ((d >> top) == prefix) atomicAdd(&hist[(d >> shift) & m], 1u);
    }
  }
  long long t = n4 * 4 + (long long)blockIdx.x * blockDim.x + threadIdx.x;
  for (; t < n; t += stride) {
    unsigned u = xs[t] & 0x7fffffffu;
    if ((u >> top) == prefix) {
      if (lds) atomicAdd(&lh[(u >> shift) & m], 1u);
      else     atomicAdd(&hist[(u >> shift) & m], 1u);
    }
  }
  if (lds) {
    __syncthreads();
    for (unsigned j = threadIdx.x; j < nb; j += blockDim.x) {
      unsigned cv = lh[j];
      if (cv) atomicAdd(&hist[j], cv);
    }
  }
}

__global__ __launch_bounds__(1024) void scan_big2_k(
    const unsigned* __restrict__ hist, const unsigned* __restrict__ chunkSums,
    Ctrl* __restrict__ ctrl)
{
  __shared__ unsigned cs[512];
  __shared__ unsigned sc[1024];
  __shared__ unsigned sel[2];
  const unsigned t = threadIdx.x;
  const unsigned oldPrefix = ctrl->prefix;
  const unsigned r = ctrl->rank;
  if (t < 512) cs[t] = chunkSums[t];
  __syncthreads();
  if (t == 0) {
    unsigned run = 0, ci = 0, cb = 0;
    for (int i = 0; i < 512; ++i) {
      unsigned cnt = cs[i];
      if (r >= run && r < run + cnt) { ci = (unsigned)i; cb = run; }
      run += cnt;
    }
    sel[0] = ci; sel[1] = cb;
  }
  __syncthreads();
  const unsigned ci = sel[0], cb = sel[1];
  const unsigned val = hist[ci * 1024u + t];
  sc[t] = val;
  __syncthreads();
  for (unsigned off = 1; off < 1024; off <<= 1) {
    unsigned add = (t >= off) ? sc[t - off] : 0u;
    __syncthreads();
    sc[t] += add;
    __syncthreads();
  }
  const unsigned incl = sc[t];
  const unsigned excl = incl - val;
  const unsigned rr = r - cb;
  if (val > 0 && rr >= excl && rr < incl) {
    ctrl->prefix = (oldPrefix << 19) | (ci * 1024u + t);
    ctrl->rank = rr - excl;
  }
}

__global__ __launch_bounds__(256) void mask_k(
    const float4* __restrict__ x4, float4* __restrict__ o4, long long n4,
    const float* __restrict__ xs, float* __restrict__ os, long long n,
    const Ctrl* __restrict__ ctrl)
{
  const float thr = ctrl->thr;
  const long long stride = (long long)gridDim.x * blockDim.x;
  long long i = (long long)blockIdx.x * blockDim.x + threadIdx.x;
  for (; i < n4; i += stride) {
    float4 v = x4[i];
    float4 w;
    w.x = (fabsf(v.x) <= thr) ? 0.0f : v.x;
    w.y = (fabsf(v.y) <= thr) ? 0.0f : v.y;
    w.z = (fabsf(v.z) <= thr) ? 0.0f : v.z;
    w.w = (fabsf(v.w) <= thr) ? 0.0f : v.w;
    o4[i] = w;
  }
  long long t = n4 * 4 + (long long)blockIdx.x * blockDim.x + threadIdx.x;
  for (; t < n; t += stride) {
    float v = xs[t];
    os[t] = (fabsf(v) <= thr) ? 0.0f : v;
  }
}

// ---------------- launch ----------------

extern "C" void kernel_launch(void* const* d_in, const int* in_sizes, int n_in,
                              void* d_out, int out_size, void* d_ws, size_t ws_size,
                              hipStream_t stream)
{
  const float* x = (const float*)d_in[0];
  const long long N = (long long)in_sizes[0];
  const long long n4 = N >> 2;
  const uint4* x4 = (const uint4*)x;
  const unsigned* xbits = (const unsigned*)x;

  // jnp.quantile fp32 index math: idx = 0.5f * f32(N-1).
  float idxf = 0.5f * (float)(N - 1);
  float lowf = floorf(idxf);
  float highf = ceilf(idxf);
  float hw = idxf - lowf;
  float lw = 1.0f - hw;
  unsigned k0 = (unsigned)lowf;
  unsigned k1 = (unsigned)highf;
  int dual = (hw != 0.0f);
  if (!dual) k1 = k0;

  const size_t needC = CAND_BYTE_OFF + ((size_t)SEGS * SEGCAP + OCAP) * 8;  // ~21 MB

  if (!dual && N < (1ll << 32) && n4 >= (1ll << 20) && ws_size >= needC) {
    unsigned* arena = (unsigned*)d_ws;
    Ctrl* c0 = (Ctrl*)arena;
    unsigned* seg_cnt   = arena + W_SEGCNT;
    unsigned* chunkSums = arena + W_CHUNK;
    unsigned* h20       = arena + W_H20;
    unsigned* h13r      = arena + W_H13R;
    unsigned* h18r      = arena + W_H18R;
    uint2* cand = (uint2*)((char*)d_ws + CAND_BYTE_OFF);

    // Guessed candidate interval around median(|N(0,1)|)=0.674490.
    // Empirical-median sigma at N=90M is ~8.3e-5, so [0.6740,0.6750) gives
    // >=6-sigma margins with only ~57K candidates. Pure performance hint:
    // scan20 verifies exact invariants; gated repair recomputes on any miss.
    float flo = 0.6740f, fhi = 0.6750f;
    unsigned Klo, Khi;
    memcpy(&Klo, &flo, 4);
    memcpy(&Khi, &fhi, 4);

    setup_k<<<1, 64, 0, stream>>>(arena, k0, Klo, Khi);
    mega_k<<<MB, MT, 0, stream>>>(x4, (float4*)d_out, n4, xbits, (float*)d_out, N,
                                  arena, cand);
    cand20_k<<<SEGS, 256, 0, stream>>>(cand, seg_cnt, c0, h20);
    scan_big1_k<<<512, 256, 0, stream>>>(h20, chunkSums);
    scan20_k<<<1, 1024, 0, stream>>>(h20, chunkSums, c0, k0, h13r, h18r);
    fixup_k<<<SEGS, 256, 0, stream>>>(cand, seg_cnt, c0, (float*)d_out);
    // gated repair chain (early-exit when flag==0)
    r13_k<<<1024, 256, 0, stream>>>(x4, n4, xbits, N, h13r, c0);
    rscan13_k<<<1, 1024, 0, stream>>>(h13r, c0, k0);
    rh18_k<<<1024, 256, 0, stream>>>(x4, n4, xbits, N, h18r, c0);
    rs18_k<<<1, 1024, 0, stream>>>(h18r, c0);
    rmask_k<<<1024, 256, 0, stream>>>((const float4*)x, (float4*)d_out, n4,
                                      x, (float*)d_out, N, c0);
    return;
  }

  // ---------- fallback: two-full-hist structure with kernel zeroing ----------
  const size_t needA = 65536 + (size_t)(1u << 19) * 4;  // 2,162,688
  char* wsb = (char*)d_ws;
  char* arena = (ws_size >= needA) ? wsb : (char*)d_out;  // d_out fully rewritten at end
  Ctrl* c0 = (ws_size >= 128) ? (Ctrl*)wsb : (Ctrl*)arena;
  Ctrl* c1 = c0 + 1;
  unsigned* chunkSums = (unsigned*)(arena + 128);
  unsigned* h1 = (unsigned*)(arena + 4096);
  unsigned* h2 = (unsigned*)(arena + 65536);
  const long long zwords = (long long)(needA - 4096) / 4;

  zero_words_k<<<512, 256, 0, stream>>>((unsigned*)(arena + 4096), zwords);
  init_ctrl_k<<<1, 64, 0, stream>>>(c0, k0, (dual ? c1 : c0), k1);

  const int nchain = dual ? 2 : 1;
  for (int chain = 0; chain < nchain; ++chain) {
    Ctrl* cc = chain ? c1 : c0;
    if (chain) zero_words_k<<<512, 256, 0, stream>>>((unsigned*)(arena + 4096), zwords);
    hist_stage_k<<<2048, 256, 0, stream>>>(x4, n4, xbits, N, h1, cc, 19, 12);
    scan_stage_k<<<1, 1024, 0, stream>>>(h1, 12, cc);
    hist_stage_k<<<2048, 256, 0, stream>>>(x4, n4, xbits, N, h2, cc, 0, 19);
    scan_big1_k<<<512, 256, 0, stream>>>(h2, chunkSums);
    scan_big2_k<<<1, 1024, 0, stream>>>(h2, chunkSums, cc);
  }
  combine_thr_k<<<1, 64, 0, stream>>>(c0, (dual ? c1 : c0), lw, hw);
  mask_k<<<2048, 256, 0, stream>>>((const float4*)x, (float4*)d_out, n4,
                                   x, (float*)d_out, N, c0);
}